// Round 4
// baseline (1419.880 us; speedup 1.0000x reference)
//
#include <hip/hip_runtime.h>
#include <math.h>
#include <stdint.h>

#define NCOL 32768
#define NROW 4
#define KSEL 1000
#define NRND (KSEL / 2)        // two exact softmax steps per reduction round
#define TPB  1024
#define NW   16                // waves per workgroup
#define CWG  8                 // workgroups per row (multi-WG kernel)
#define EPTM (NCOL / (CWG * TPB))   // 4 elements/thread in multi-WG kernel
#define EPT  32                // elements/thread in fallback single-WG kernel

// d_ws layout (u32 words), all zeroed at launch:
//   cnt [NROW][1024]  @ 0       per-round arrival counters (or packed count<<8|arrival)
//   s1  [NROW][1024]  @ 4096    per-round global S1 accumulators (f32 atomicAdd)
//   s2  [NROW][1024]  @ 8192    per-round global S2 accumulators
//   misc[NROW][8]     @ 12288   [0]=mapped-uint max(logits), [1]=SE=sum exp(logits) (f32)
//   tie [NROW][8]     @ 12320   per-WG tie counts
#define WS_WORDS 12352
#define WS_BYTES (WS_WORDS * 4)

#define SCOPE __HIP_MEMORY_SCOPE_AGENT

// ---- DPP 64-lane sum (rocPRIM pattern): total lands in lane 63 ----
template<int ctrl, int rmask, int bmask>
__device__ __forceinline__ float dppmv(float x) {
  return __int_as_float(__builtin_amdgcn_update_dpp(
      0, __float_as_int(x), ctrl, rmask, bmask, false));
}
__device__ __forceinline__ float dpp_wave_sum(float v) {
  v += dppmv<0x111, 0xf, 0xf>(v);
  v += dppmv<0x112, 0xf, 0xf>(v);
  v += dppmv<0x114, 0xf, 0xe>(v);
  v += dppmv<0x118, 0xf, 0xc>(v);
  v += dppmv<0x142, 0xa, 0xf>(v);
  v += dppmv<0x143, 0xc, 0xf>(v);
  return v;   // lane 63 holds the wave total
}

__device__ __forceinline__ float wred_sum(float v) {
#pragma unroll
  for (int m = 32; m; m >>= 1) v += __shfl_xor(v, m, 64);
  return v;
}
__device__ __forceinline__ float wred_max(float v) {
#pragma unroll
  for (int m = 32; m; m >>= 1) v = fmaxf(v, __shfl_xor(v, m, 64));
  return v;
}
__device__ __forceinline__ int wred_sum_i(int v) {
#pragma unroll
  for (int m = 32; m; m >>= 1) v += __shfl_xor(v, m, 64);
  return v;
}
__device__ __forceinline__ float sum16(const float4* rp) {
  float4 a = rp[0], b = rp[1], c = rp[2], d = rp[3];
  float sa = (a.x + a.y) + (a.z + a.w);
  float sb = (b.x + b.y) + (b.z + b.w);
  float sc = (c.x + c.y) + (c.z + c.w);
  float sd = (d.x + d.y) + (d.z + d.w);
  return (sa + sb) + (sc + sd);
}

// monotone float<->uint map for atomicMax over signed floats
__device__ __forceinline__ uint32_t fmap(float f) {
  int b = __float_as_int(f);
  return b >= 0 ? ((uint32_t)b ^ 0x80000000u) : ~(uint32_t)b;
}
__device__ __forceinline__ float funmap(uint32_t u) {
  int b = (u & 0x80000000u) ? (int)(u ^ 0x80000000u) : ~(int)u;
  return __int_as_float(b);
}

__device__ __forceinline__ void addf_g(float* p, float v) {
  __hip_atomic_fetch_add(p, v, __ATOMIC_RELAXED, SCOPE);
}
__device__ __forceinline__ float ldf_g(const float* p) {
  return __hip_atomic_load(p, __ATOMIC_RELAXED, SCOPE);
}
// release arrival, acquire spin until low byte == CWG; returns full value
__device__ __forceinline__ uint32_t arrive_spin_acq(uint32_t* slot, uint32_t inc) {
  __hip_atomic_fetch_add(slot, inc, __ATOMIC_RELEASE, SCOPE);
  uint32_t v;
  do { v = __hip_atomic_load(slot, __ATOMIC_ACQUIRE, SCOPE); } while ((v & 0xFFu) != CWG);
  return v;
}
// relaxed variant (single-variable rounds: packed count needs no cross-var ordering)
__device__ __forceinline__ uint32_t arrive_spin_rel(uint32_t* slot, uint32_t inc) {
  __hip_atomic_fetch_add(slot, inc, __ATOMIC_RELAXED, SCOPE);
  uint32_t v;
  do { v = __hip_atomic_load(slot, __ATOMIC_RELAXED, SCOPE); } while ((v & 0xFFu) != CWG);
  return v;
}

// ==================== multi-WG kernel: 8 WGs per row ====================
__global__ __launch_bounds__(TPB, 4) void selhead_multi(
    const float* __restrict__ logits,
    const float* __restrict__ gumbel,
    float* __restrict__ out,
    uint32_t* __restrict__ ws)
{
  const int row  = blockIdx.x >> 3;       // CWG == 8
  const int cwg  = blockIdx.x & 7;
  const int tid  = threadIdx.x;
  const int lane = tid & 63;
  const int wv   = tid >> 6;
  const long rowoff = (long)row * NCOL;
  const float* lrow = logits + rowoff;
  const float* grow = gumbel + rowoff;
  const int gbase = cwg * (TPB * EPTM) + tid * EPTM;   // this thread's 4 columns

  uint32_t* cnt  = ws + row * 1024;
  float*    s1g  = (float*)(ws + 4096) + row * 1024;
  float*    s2g  = (float*)(ws + 8192) + row * 1024;
  uint32_t* misc = ws + 12288 + row * 8;
  uint32_t* tieg = ws + 12320 + row * 8;

  __shared__ __align__(16) float redW1[NW];
  __shared__ __align__(16) float redW2[NW];
  __shared__ __align__(16) float redW3[NW];
  __shared__ __align__(16) float redW4[NW];
  __shared__ int   redI[NW];
  __shared__ int   swtot[NW];
  __shared__ float bcast[4];
  __shared__ int   bcasti[2];

  float w[EPTM];   // unnormalized softmax weights (no shift: exp(s0) safe in fp32)
  float k[EPTM];   // khot accumulator

  // ---------- setup: load, w = exp(l+g), partial S1/S2/SE/maxL ----------
  const float4 lv = *(const float4*)(lrow + gbase);
  const float4 gv = *(const float4*)(grow + gbase);
  float l[EPTM] = {lv.x, lv.y, lv.z, lv.w};
  float mxl = fmaxf(fmaxf(l[0], l[1]), fmaxf(l[2], l[3]));
  float pse = 0.f, s1p = 0.f, s2p = 0.f;
#pragma unroll
  for (int j = 0; j < EPTM; ++j) {
    pse += expf(l[j]);
    w[j] = expf(l[j] + ((const float*)&gv)[j]);
    s1p += w[j];
    s2p = fmaf(w[j], w[j], s2p);
    k[j] = 0.f;
  }
  {
    float r1 = dpp_wave_sum(s1p);
    float r2 = dpp_wave_sum(s2p);
    float r3 = dpp_wave_sum(pse);
    float rm = wred_max(mxl);
    if (lane == 63) { redW1[wv] = r1; redW2[wv] = r2; redW3[wv] = r3; }
    if (lane == 0)  { redW4[wv] = rm; }
  }
  __syncthreads();
  if (tid == 0) {
    float s1t = sum16((const float4*)redW1);
    float s2t = sum16((const float4*)redW2);
    float set = sum16((const float4*)redW3);
    float mlt = -INFINITY;
#pragma unroll
    for (int i = 0; i < NW; ++i) mlt = fmaxf(mlt, redW4[i]);
    __hip_atomic_fetch_max(misc + 0, fmap(mlt), __ATOMIC_RELAXED, SCOPE);
    addf_g((float*)(misc + 1), set);
    addf_g(&s1g[0], s1t);
    addf_g(&s2g[0], s2t);
    arrive_spin_acq(&cnt[0], 1u);
    bcast[0] = ldf_g(&s1g[0]);
    bcast[1] = ldf_g(&s2g[0]);
    bcast[2] = ldf_g((const float*)(misc + 1));
    bcast[3] = funmap(__hip_atomic_load(misc + 0, __ATOMIC_RELAXED, SCOPE));
  }
  __syncthreads();
  float S1 = bcast[0];
  float S2 = bcast[1];
  const float logZ = logf(bcast[2]);    // logits in [-5,5]: no shift needed
  const float ML   = bcast[3];

  if (cwg == 0 && tid == 0) out[row] = 1.0f / (1.0f + expf(-ML));

  // ---------- main loop: NRND rounds, 2 exact softmax steps each ----------
  // W_B = S1 - S2/S1 (exact second-step normalizer from moments)
  for (int rd = 1; rd <= NRND; ++rd) {
    const float WB = S1 - S2 / S1;
    const float rA = 1.0f / S1;
    const float rB = 1.0f / WB;
    float a = 0.f, b = 0.f;
#pragma unroll
    for (int j = 0; j < EPTM; ++j) {
      float t = w[j] * rA;                       // step A: p = w/S1
      k[j] += t;
      float u = fmaxf(fmaf(-t, w[j], w[j]), 0.f);
      float t2 = u * rB;                         // step B: p = u/WB
      k[j] += t2;
      u = fmaxf(fmaf(-t2, u, u), 0.f);
      w[j] = u;
      a += u;
      b = fmaf(u, u, b);
    }
    float r1 = dpp_wave_sum(a);
    float r2 = dpp_wave_sum(b);
    if (lane == 63) { redW1[wv] = r1; redW2[wv] = r2; }
    __syncthreads();
    if (tid == 0) {
      addf_g(&s1g[rd], sum16((const float4*)redW1));
      addf_g(&s2g[rd], sum16((const float4*)redW2));
      arrive_spin_acq(&cnt[rd], 1u);
      bcast[0] = ldf_g(&s1g[rd]);
      bcast[1] = ldf_g(&s2g[rd]);
    }
    __syncthreads();
    S1 = bcast[0];
    S2 = bcast[1];
  }

  // ---------- top-KSEL threshold: 32 global radix rounds ----------
  uint32_t ku[EPTM];
#pragma unroll
  for (int j = 0; j < EPTM; ++j) ku[j] = __float_as_uint(k[j]);

  uint32_t T = 0;
  for (int bit = 31; bit >= 0; --bit) {
    const int ridx = NRND + 1 + (31 - bit);
    const uint32_t cand = T | (1u << bit);
    int c = 0;
#pragma unroll
    for (int j = 0; j < EPTM; ++j) c += (ku[j] >= cand) ? 1 : 0;
    int wc = wred_sum_i(c);
    if (lane == 0) redI[wv] = wc;
    __syncthreads();
    if (tid == 0) {
      int tot = 0;
#pragma unroll
      for (int i = 0; i < NW; ++i) tot += redI[i];
      uint32_t v = arrive_spin_rel(&cnt[ridx], ((uint32_t)tot << 8) | 1u);
      bcasti[0] = (int)(v >> 8);
    }
    __syncthreads();
    if (bcasti[0] >= KSEL) T = cand;      // uniform across all WGs of the row
  }
  // strictly-greater count
  int rneed;
  {
    int cg = 0;
#pragma unroll
    for (int j = 0; j < EPTM; ++j) cg += (ku[j] > T) ? 1 : 0;
    int wcg = wred_sum_i(cg);
    if (lane == 0) redI[wv] = wcg;
    __syncthreads();
    if (tid == 0) {
      int tot = 0;
#pragma unroll
      for (int i = 0; i < NW; ++i) tot += redI[i];
      uint32_t v = arrive_spin_rel(&cnt[NRND + 33], ((uint32_t)tot << 8) | 1u);
      bcasti[0] = (int)(v >> 8);
    }
    __syncthreads();
    rneed = KSEL - bcasti[0];             // ties (== T) to take, lowest index first
  }

  // ---------- tie ranking: global index-ordered prefix ----------
  int tcnt = 0;
#pragma unroll
  for (int j = 0; j < EPTM; ++j) tcnt += (ku[j] == T) ? 1 : 0;
  int isc = tcnt;
#pragma unroll
  for (int d = 1; d < 64; d <<= 1) {
    int nb = __shfl_up(isc, d, 64);
    if (lane >= d) isc += nb;
  }
  if (lane == 63) swtot[wv] = isc;
  __syncthreads();
  if (tid == 0) {
    int wgtot = 0;
#pragma unroll
    for (int i = 0; i < NW; ++i) wgtot += swtot[i];
    __hip_atomic_store(tieg + cwg, (uint32_t)wgtot, __ATOMIC_RELAXED, SCOPE);
    arrive_spin_acq(&cnt[NRND + 34], 1u);
    int woff = 0;
    for (int i = 0; i < cwg; ++i)
      woff += (int)__hip_atomic_load(tieg + i, __ATOMIC_RELAXED, SCOPE);
    bcasti[1] = woff;
  }
  __syncthreads();
  int woff_in = 0;
#pragma unroll
  for (int i = 0; i < NW; ++i) if (i < wv) woff_in += swtot[i];
  int rk = bcasti[1] + woff_in + (isc - tcnt);   // global exclusive tie-rank

  // ---------- outputs: values[4] | logprobs[4*NCOL] | actions[4*NCOL] ----------
  float* outlp = out + NROW + rowoff + gbase;
  float* outac = out + NROW + (long)NROW * NCOL + rowoff + gbase;
  float a_[EPTM];
#pragma unroll
  for (int j = 0; j < EPTM; ++j) {
    const uint32_t u = ku[j];
    const bool sel = (u > T) || ((u == T) && (rk < rneed));
    if (u == T) ++rk;
    a_[j] = sel ? ((1.0f - k[j]) + k[j]) : 0.0f;
  }
  float4 ac; ac.x = a_[0]; ac.y = a_[1]; ac.z = a_[2]; ac.w = a_[3];
  float4 lp;
  lp.x = (l[0] - logZ) * ac.x;
  lp.y = (l[1] - logZ) * ac.y;
  lp.z = (l[2] - logZ) * ac.z;
  lp.w = (l[3] - logZ) * ac.w;
  *(float4*)outlp = lp;
  *(float4*)outac = ac;
}

// ==================== fallback: R3 single-WG kernel (verified) ====================
__global__ __launch_bounds__(TPB, 4) void selhead_kernel(
    const float* __restrict__ logits,
    const float* __restrict__ gumbel,
    float* __restrict__ out)
{
  const int row  = blockIdx.x;
  const int tid  = threadIdx.x;
  const int lane = tid & 63;
  const int wv   = tid >> 6;
  const long rowoff = (long)row * NCOL;
  const float* lrow = logits + rowoff;
  const float* grow = gumbel + rowoff;
  const int base = tid * EPT;

  __shared__ __align__(16) float redA[NW];
  __shared__ __align__(16) float redB[NW];
  __shared__ __align__(16) float redW1[2][NW];
  __shared__ __align__(16) float redW2[2][NW];
  __shared__ int  redI[2][NW];
  __shared__ int  swtot[NW];

  float w[EPT];
  float k[EPT];

  float mxl = -INFINITY, mxs = -INFINITY;
#pragma unroll
  for (int j = 0; j < EPT; j += 4) {
    const float4 lv = *(const float4*)(lrow + base + j);
    const float4 gv = *(const float4*)(grow + base + j);
    k[j+0] = lv.x; k[j+1] = lv.y; k[j+2] = lv.z; k[j+3] = lv.w;
    w[j+0] = lv.x + gv.x; w[j+1] = lv.y + gv.y;
    w[j+2] = lv.z + gv.z; w[j+3] = lv.w + gv.w;
    mxl = fmaxf(mxl, fmaxf(fmaxf(lv.x, lv.y), fmaxf(lv.z, lv.w)));
    mxs = fmaxf(mxs, fmaxf(fmaxf(w[j+0], w[j+1]), fmaxf(w[j+2], w[j+3])));
  }
  {
    float wm_s = wred_max(mxs);
    float wm_l = wred_max(mxl);
    if (lane == 0) { redA[wv] = wm_s; redB[wv] = wm_l; }
  }
  __syncthreads();
  float M0 = -INFINITY, ML = -INFINITY;
#pragma unroll
  for (int i = 0; i < NW; ++i) {
    M0 = fmaxf(M0, redA[i]);
    ML = fmaxf(ML, redB[i]);
  }
  __syncthreads();

  float pse = 0.f;
  float pa0 = 0.f, pa1 = 0.f;
  float pb0 = 0.f, pb1 = 0.f;
#pragma unroll
  for (int j = 0; j < EPT; j += 2) {
    pse += expf(k[j+0] - ML); pse += expf(k[j+1] - ML);
    w[j+0] = expf(w[j+0] - M0); w[j+1] = expf(w[j+1] - M0);
    pa0 += w[j+0];                 pa1 += w[j+1];
    pb0 = fmaf(w[j+0], w[j+0], pb0);
    pb1 = fmaf(w[j+1], w[j+1], pb1);
    k[j+0] = 0.f; k[j+1] = 0.f;
  }
  float s1 = pa0 + pa1;
  float s2 = pb0 + pb1;
  {
    float wse = wred_sum(pse);
    if (lane == 0) redA[wv] = wse;
  }
  __syncthreads();
  float SE = sum16((const float4*)redA);
  const float logZ = ML + logf(SE);

  for (int rd = 0; rd < NRND; ++rd) {
    float r1 = dpp_wave_sum(s1);
    float r2 = dpp_wave_sum(s2);
    if (lane == 63) { redW1[rd & 1][wv] = r1; redW2[rd & 1][wv] = r2; }
    __syncthreads();
    const float S1 = sum16((const float4*)redW1[rd & 1]);
    const float S2 = sum16((const float4*)redW2[rd & 1]);
    const float WB = S1 - S2 / S1;
    const float rA = 1.0f / S1;
    const float rB = 1.0f / WB;
    float a0 = 0.f, a1 = 0.f;
    float b0 = 0.f, b1 = 0.f;
#pragma unroll
    for (int j = 0; j < EPT; j += 2) {
      float pA0 = w[j+0] * rA,  pA1 = w[j+1] * rA;
      k[j+0] += pA0;            k[j+1] += pA1;
      float u0 = fmaxf(fmaf(-pA0, w[j+0], w[j+0]), 0.f);
      float u1 = fmaxf(fmaf(-pA1, w[j+1], w[j+1]), 0.f);
      float pB0 = u0 * rB,      pB1 = u1 * rB;
      k[j+0] += pB0;            k[j+1] += pB1;
      u0 = fmaxf(fmaf(-pB0, u0, u0), 0.f);
      u1 = fmaxf(fmaf(-pB1, u1, u1), 0.f);
      w[j+0] = u0;              w[j+1] = u1;
      a0 += u0;                 a1 += u1;
      b0 = fmaf(u0, u0, b0);    b1 = fmaf(u1, u1, b1);
    }
    s1 = a0 + a1;
    s2 = b0 + b1;
  }

  uint32_t ku[EPT];
#pragma unroll
  for (int j = 0; j < EPT; ++j) ku[j] = __float_as_uint(k[j]);

  int step = 0;
  uint32_t T = 0;
  for (int bit = 31; bit >= 0; --bit, ++step) {
    const uint32_t cand = T | (1u << bit);
    int c = 0;
#pragma unroll
    for (int j = 0; j < EPT; ++j) c += (ku[j] >= cand) ? 1 : 0;
    int wc = wred_sum_i(c);
    if (lane == 0) redI[step & 1][wv] = wc;
    __syncthreads();
    int tot = 0;
#pragma unroll
    for (int i = 0; i < NW; ++i) tot += redI[step & 1][i];
    if (tot >= KSEL) T = cand;
  }
  {
    int cg = 0;
#pragma unroll
    for (int j = 0; j < EPT; ++j) cg += (ku[j] > T) ? 1 : 0;
    int wcg = wred_sum_i(cg);
    if (lane == 0) redI[step & 1][wv] = wcg;
  }
  __syncthreads();
  int c_gt = 0;
#pragma unroll
  for (int i = 0; i < NW; ++i) c_gt += redI[step & 1][i];
  const int rneed = KSEL - c_gt;

  int tcnt = 0;
#pragma unroll
  for (int j = 0; j < EPT; ++j) tcnt += (ku[j] == T) ? 1 : 0;
  int isc = tcnt;
#pragma unroll
  for (int d = 1; d < 64; d <<= 1) {
    int nb = __shfl_up(isc, d, 64);
    if (lane >= d) isc += nb;
  }
  if (lane == 63) swtot[wv] = isc;
  __syncthreads();
  int woff = 0;
#pragma unroll
  for (int i = 0; i < NW; ++i) if (i < wv) woff += swtot[i];
  int rk = woff + (isc - tcnt);

  float* outlp = out + NROW + rowoff;
  float* outac = out + NROW + (long)NROW * NCOL + rowoff;
  if (tid == 0) out[row] = 1.0f / (1.0f + expf(-ML));

#pragma unroll
  for (int j = 0; j < EPT; ++j) {
    const uint32_t u = ku[j];
    const bool sel = (u > T) || ((u == T) && (rk < rneed));
    if (u == T) ++rk;
    w[j] = sel ? ((1.0f - k[j]) + k[j]) : 0.0f;
  }
#pragma unroll
  for (int j = 0; j < EPT; j += 4) {
    const float4 lv = *(const float4*)(lrow + base + j);
    float4 ac; ac.x = w[j+0]; ac.y = w[j+1]; ac.z = w[j+2]; ac.w = w[j+3];
    float4 lp;
    lp.x = (lv.x - logZ) * ac.x;
    lp.y = (lv.y - logZ) * ac.y;
    lp.z = (lv.z - logZ) * ac.z;
    lp.w = (lv.w - logZ) * ac.w;
    *(float4*)(outlp + base + j) = lp;
    *(float4*)(outac + base + j) = ac;
  }
}

extern "C" void kernel_launch(void* const* d_in, const int* in_sizes, int n_in,
                              void* d_out, int out_size, void* d_ws, size_t ws_size,
                              hipStream_t stream) {
  const float* logits = (const float*)d_in[0];
  const float* gumbel = (const float*)d_in[1];
  float* out = (float*)d_out;
  if (ws_size >= (size_t)WS_BYTES) {
    hipMemsetAsync(d_ws, 0, WS_BYTES, stream);
    hipLaunchKernelGGL(selhead_multi, dim3(NROW * CWG), dim3(TPB), 0, stream,
                       logits, gumbel, out, (uint32_t*)d_ws);
  } else {
    hipLaunchKernelGGL(selhead_kernel, dim3(NROW), dim3(TPB), 0, stream,
                       logits, gumbel, out);
  }
}

// Round 5
// 98.907 us; speedup vs baseline: 14.3557x; 14.3557x over previous
//
#include <hip/hip_runtime.h>
#include <math.h>
#include <stdint.h>

#define NCOL 32768
#define NROW 4
#define KSEL 1000
#define TPB  1024
#define EPT  32          // elements per thread: 1024*32 = 32768
#define NW   16          // waves per workgroup

// Insight (R5): the reference's 1000-iteration Gumbel-topk relaxation is only
// used through (a) actions = khot_hard - sg(khot) + khot, which is numerically
// exactly the hard top-1000 indicator (0 exactly / 1 +- 1.2e-7), and
// (b) the selected SET, which equals top-1000 of s0 = logits+gumbel:
// all elements share the normalizer sequence W_t and x -> x(1-x/W) is strictly
// increasing below W/2, so khot is strictly monotone in s0 at the selection
// boundary (spiking items all end with khot ~ 1, far above the cut).
// Therefore: no simulation needed. Top-1000 of s0 with index tie-break,
// logprobs = (l - logZ) * action, values = sigmoid(max l).

__device__ __forceinline__ float wred_sum(float v) {
#pragma unroll
  for (int m = 32; m; m >>= 1) v += __shfl_xor(v, m, 64);
  return v;
}
__device__ __forceinline__ float wred_max(float v) {
#pragma unroll
  for (int m = 32; m; m >>= 1) v = fmaxf(v, __shfl_xor(v, m, 64));
  return v;
}
__device__ __forceinline__ int wred_sum_i(int v) {
#pragma unroll
  for (int m = 32; m; m >>= 1) v += __shfl_xor(v, m, 64);
  return v;
}
// deterministic tree-sum of 16 floats (same order in every thread)
__device__ __forceinline__ float sum16(const float4* rp) {
  float4 a = rp[0], b = rp[1], c = rp[2], d = rp[3];
  float sa = (a.x + a.y) + (a.z + a.w);
  float sb = (b.x + b.y) + (b.z + b.w);
  float sc = (c.x + c.y) + (c.z + c.w);
  float sd = (d.x + d.y) + (d.z + d.w);
  return (sa + sb) + (sc + sd);
}
// monotone float->uint map (signed floats, no NaN): order(u) == order(f)
__device__ __forceinline__ uint32_t fmap(float f) {
  int b = __float_as_int(f);
  return b >= 0 ? ((uint32_t)b ^ 0x80000000u) : ~(uint32_t)b;
}

__global__ __launch_bounds__(TPB, 4) void selhead_kernel(
    const float* __restrict__ logits,
    const float* __restrict__ gumbel,
    float* __restrict__ out)
{
  const int row  = blockIdx.x;
  const int tid  = threadIdx.x;
  const int lane = tid & 63;
  const int wv   = tid >> 6;
  const long rowoff = (long)row * NCOL;
  const float* lrow = logits + rowoff;
  const float* grow = gumbel + rowoff;
  const int base = tid * EPT;

  __shared__ __align__(16) float redA[NW];
  __shared__ __align__(16) float redB[NW];
  __shared__ int  redI[2][NW];
  __shared__ int  swtot[NW];

  float    l[EPT];    // logits (kept for the output phase)
  uint32_t ku[EPT];   // monotone-mapped s0 = logits + gumbel

  // ---------- Phase A: load; u = fmap(l+g); SE = sum exp(l); ML = max l ----
  // logits ~ N(0,1): |l| < ~6, exp(l) < ~400, SE ~ 5.4e4 — no shift needed.
  float mxl = -INFINITY;
  float pse = 0.f;
#pragma unroll
  for (int j = 0; j < EPT; j += 4) {
    const float4 lv = *(const float4*)(lrow + base + j);
    const float4 gv = *(const float4*)(grow + base + j);
    l[j+0] = lv.x; l[j+1] = lv.y; l[j+2] = lv.z; l[j+3] = lv.w;
    ku[j+0] = fmap(lv.x + gv.x); ku[j+1] = fmap(lv.y + gv.y);
    ku[j+2] = fmap(lv.z + gv.z); ku[j+3] = fmap(lv.w + gv.w);
    mxl = fmaxf(mxl, fmaxf(fmaxf(lv.x, lv.y), fmaxf(lv.z, lv.w)));
    pse += expf(lv.x); pse += expf(lv.y);
    pse += expf(lv.z); pse += expf(lv.w);
  }
  {
    float wm = wred_max(mxl);
    float ws = wred_sum(pse);
    if (lane == 0) { redA[wv] = ws; redB[wv] = wm; }
  }
  __syncthreads();
  const float SE = sum16((const float4*)redA);
  float ML = -INFINITY;
#pragma unroll
  for (int i = 0; i < NW; ++i) ML = fmaxf(ML, redB[i]);
  const float logZ = logf(SE);

  if (tid == 0) out[row] = 1.0f / (1.0f + expf(-ML));   // values

  // ---------- Phase B: top-KSEL threshold, 32-round radix binary search ----
  int step = 0;
  uint32_t T = 0;
  for (int bit = 31; bit >= 0; --bit, ++step) {
    const uint32_t cand = T | (1u << bit);
    int c = 0;
#pragma unroll
    for (int j = 0; j < EPT; ++j) c += (ku[j] >= cand) ? 1 : 0;
    int wc = wred_sum_i(c);
    if (lane == 0) redI[step & 1][wv] = wc;
    __syncthreads();
    int tot = 0;
#pragma unroll
    for (int i = 0; i < NW; ++i) tot += redI[step & 1][i];
    if (tot >= KSEL) T = cand;   // uniform decision in all threads
  }
  // strictly-greater count -> number of ties to accept (lowest index first)
  {
    int cg = 0;
#pragma unroll
    for (int j = 0; j < EPT; ++j) cg += (ku[j] > T) ? 1 : 0;
    int wcg = wred_sum_i(cg);
    if (lane == 0) redI[step & 1][wv] = wcg;
  }
  __syncthreads();
  int c_gt = 0;
#pragma unroll
  for (int i = 0; i < NW; ++i) c_gt += redI[step & 1][i];
  const int rneed = KSEL - c_gt;

  // index-ordered exclusive prefix of tie counts (thread chunks contiguous)
  int tcnt = 0;
#pragma unroll
  for (int j = 0; j < EPT; ++j) tcnt += (ku[j] == T) ? 1 : 0;
  int isc = tcnt;
#pragma unroll
  for (int d = 1; d < 64; d <<= 1) {
    int nb = __shfl_up(isc, d, 64);
    if (lane >= d) isc += nb;
  }
  if (lane == 63) swtot[wv] = isc;
  __syncthreads();
  int woff = 0;
#pragma unroll
  for (int i = 0; i < NW; ++i) if (i < wv) woff += swtot[i];
  int rk = woff + (isc - tcnt);   // global exclusive tie-rank at chunk start

  // ---------- Phase C: outputs ----------
  // out layout: values[4] | logprobs[4*NCOL] | actions[4*NCOL]
  float* outlp = out + NROW + rowoff;
  float* outac = out + NROW + (long)NROW * NCOL + rowoff;
#pragma unroll
  for (int j = 0; j < EPT; j += 4) {
    float4 ac, lp;
    float a[4];
#pragma unroll
    for (int q = 0; q < 4; ++q) {
      const uint32_t u = ku[j+q];
      const bool sel = (u > T) || ((u == T) && (rk < rneed));
      if (u == T) ++rk;
      a[q] = sel ? 1.0f : 0.0f;
    }
    ac.x = a[0]; ac.y = a[1]; ac.z = a[2]; ac.w = a[3];
    lp.x = (l[j+0] - logZ) * a[0];
    lp.y = (l[j+1] - logZ) * a[1];
    lp.z = (l[j+2] - logZ) * a[2];
    lp.w = (l[j+3] - logZ) * a[3];
    *(float4*)(outlp + base + j) = lp;
    *(float4*)(outac + base + j) = ac;
  }
}

extern "C" void kernel_launch(void* const* d_in, const int* in_sizes, int n_in,
                              void* d_out, int out_size, void* d_ws, size_t ws_size,
                              hipStream_t stream) {
  const float* logits = (const float*)d_in[0];
  const float* gumbel = (const float*)d_in[1];
  float* out = (float*)d_out;
  hipLaunchKernelGGL(selhead_kernel, dim3(NROW), dim3(TPB), 0, stream,
                     logits, gumbel, out);
}